// Round 18
// baseline (830.942 us; speedup 1.0000x reference)
//
#include <hip/hip_runtime.h>
#include <hip/hip_cooperative_groups.h>
#include <hip/hip_fp16.h>
#include <math.h>

namespace cg = cooperative_groups;

#define CUTOFF 5.0f
#define H 64
#define FIN 16
#define NLAYERS 3
#define LUTN 2048          // intervals; table has LUTN+1 entries
#define LUTSTRIDE 2052     // padded per-layer stride
#define ASTRIDE 72         // LDS row stride in halves (144B, 16B-aligned)
#define NPART 8            // histogram partitions (== XCD count)
#define LUTB 9             // lut blocks per layer (9*256 >= 2049)
#define PREPB 1024         // cooperative prep grid (4 blocks/CU — co-resident)

// 1/sqrt(1 + 1e-3)  (BN inference, moving mean 0 / var 1)
#define BN_INV 0.999500374750f

typedef _Float16 h8 __attribute__((ext_vector_type(8)));
typedef _Float16 h2 __attribute__((ext_vector_type(2)));
typedef float f32x4 __attribute__((ext_vector_type(4)));

__device__ __forceinline__ float softplus_f(float x) {
    return fmaxf(x, 0.f) + __logf(1.f + __expf(-fabsf(x)));
}

// ---- K1: mega setup (R13 form). Block roles by blockIdx range:
//   [0, nbE)                 embed 4 nodes/block -> h0 fp16; zero 32 cnt8 ints
//   [nbE, nbE+27)            LUT: inline wsum/bsum in LDS, 256 entries/block
//   [nbE+27, nbE+39)         weight swizzle Wsw + b2p
__global__ __launch_bounds__(256)
void k_setup(const float* __restrict__ x, const float* __restrict__ emb_W,
             const float* __restrict__ emb_b, _Float16* __restrict__ h0,
             const float* __restrict__ fW1, const float* __restrict__ fb1,
             const float* __restrict__ fW2, const float* __restrict__ fb2,
             const float* __restrict__ iW1, const float* __restrict__ iW2,
             const float* __restrict__ bn_g, const float* __restrict__ bn_b,
             const float* __restrict__ ib2, h8* __restrict__ Wsw,
             float* __restrict__ b2p, float* __restrict__ lut,
             int* __restrict__ cnt8, int N) {
    __shared__ float swsum[64];
    __shared__ float sbsum;
    int b = blockIdx.x;
    int t = threadIdx.x;
    int nbE = (N + 3) / 4;
    if (b < nbE) {
        int ci = b * 32 + t;
        if (t < 32 && ci < NPART * N) cnt8[ci] = 0;
        int lane = t & 63;
        int w = t >> 6;
        int node = b * 4 + w;
        if (node < N) {
            float acc = emb_b[lane];
#pragma unroll
            for (int k = 0; k < FIN; k++) acc += x[node * FIN + k] * emb_W[k * H + lane];
            h0[(size_t)node * H + lane] = (_Float16)acc;
        }
    } else if (b < nbE + NLAYERS * LUTB) {
        int lb = b - nbE;
        int l = lb / LUTB, part = lb % LUTB;
        if (t < 64) {
            float s = 0.f;
            for (int j = 0; j < H; j++) s += fW2[l * H * H + t * H + j];
            swsum[t] = s;
        }
        if (t == 64) {
            float s = 0.f;
            for (int j = 0; j < H; j++) s += fb2[l * H + j];
            sbsum = s;
        }
        __syncthreads();
        int i = part * 256 + t;
        if (i <= LUTN) {
            float d = (float)i * (CUTOFF / (float)LUTN);
            float scaled = d * (2.0f / CUTOFF) - 1.0f;
            float cut = 0.5f * (__cosf(d * (3.14159265358979f / CUTOFF)) + 1.0f);
            if (d > CUTOFF) cut = 0.f;
            float s = 0.f;
            for (int hh = 0; hh < H; hh++) {
                int wi = l * H + hh;
                s += tanhf(scaled * fW1[wi] + fb1[wi]) * swsum[hh];
            }
            lut[l * LUTSTRIDE + i] = cut * (s + sbsum);
        }
    } else {
        int tid = (b - nbE - NLAYERS * LUTB) * 256 + t;
        if (tid < NLAYERS * H)
            b2p[tid] = ib2[tid] * BN_INV * bn_g[tid] + bn_b[tid];
        if (tid < NLAYERS * 2 * 8 * 64) {
            int lane = tid & 63;
            int frag = (tid >> 6) & 7;
            int mat  = (tid >> 9) & 1;
            int l    = tid >> 10;
            int kt = frag >> 2, nt = frag & 3;
            int n = nt * 16 + (lane & 15);
            int k0 = kt * 32 + (lane >> 4) * 8;
            const float* W = (mat ? iW2 : iW1) + l * H * H;
            float scale = mat ? BN_INV * bn_g[l * H + n] : 1.0f;
            h8 v;
#pragma unroll
            for (int j = 0; j < 8; j++) v[j] = (_Float16)(W[(k0 + j) * H + n] * scale);
            Wsw[tid] = v;
        }
    }
}

// ---- Cooperative prep: hist -> sync -> chunk sums -> sync -> scan+bases ->
// sync -> scatter. Grid-stride at PREPB blocks (co-resident). Partition p for
// an edge chunk is (chunk & 7) in BOTH hist and scatter phases.
__global__ __launch_bounds__(256)
void k_prep(const int* __restrict__ ei, const float* __restrict__ dist,
            int* __restrict__ cnt8, unsigned char* __restrict__ rank8,
            int* __restrict__ row_ptr, int* __restrict__ basep,
            int* __restrict__ bsums, unsigned int* __restrict__ recs,
            int N, int E) {
    cg::grid_group grid = cg::this_grid();
    __shared__ int sd[256];
    __shared__ int ex[512];
    int t = threadIdx.x;
    int nblk = gridDim.x;
    int nb_edge = (E + 255) / 256;
    int nb_row  = (N + 255) / 256;

    // phase 1: partitioned histogram; atomic return = within-(p,row) rank
    for (int b = blockIdx.x; b < nb_edge; b += nblk) {
        int e = b * 256 + t;
        if (e < E) {
            int p = b & (NPART - 1);
            int r = atomicAdd(&cnt8[(size_t)p * N + ei[e]], 1);
            rank8[e] = (unsigned char)r;
        }
    }
    grid.sync();

    // phase 2: per-256-row chunk sums of row totals
    for (int b = blockIdx.x; b < nb_row; b += nblk) {
        int i = b * 256 + t;
        int v = 0;
        if (i < N) {
#pragma unroll
            for (int p = 0; p < NPART; p++) v += cnt8[(size_t)p * N + i];
        }
        sd[t] = v;
        __syncthreads();
        for (int off = 128; off > 0; off >>= 1) {
            if (t < off) sd[t] += sd[t + off];
            __syncthreads();
        }
        if (t == 0) bsums[b] = sd[0];
        __syncthreads();
    }
    grid.sync();

    // phase 3: redundant scan of chunk sums + per-chunk scan -> row_ptr, basep
    for (int b = blockIdx.x; b < nb_row; b += nblk) {
        int a0 = (2 * t     < nb_row) ? bsums[2 * t]     : 0;
        int a1 = (2 * t + 1 < nb_row) ? bsums[2 * t + 1] : 0;
        sd[t] = a0 + a1;
        __syncthreads();
        for (int off = 1; off < 256; off <<= 1) {
            int v = (t >= off) ? sd[t - off] : 0;
            __syncthreads();
            sd[t] += v;
            __syncthreads();
        }
        int pairExcl = (t == 0) ? 0 : sd[t - 1];
        ex[2 * t] = pairExcl;
        ex[2 * t + 1] = pairExcl + a0;
        __syncthreads();
        int myBase = ex[b];
        __syncthreads();

        int i = b * 256 + t;
        int c[NPART];
        int v = 0;
        if (i < N) {
#pragma unroll
            for (int p = 0; p < NPART; p++) { c[p] = cnt8[(size_t)p * N + i]; v += c[p]; }
        }
        sd[t] = v;
        __syncthreads();
        for (int off = 1; off < 256; off <<= 1) {
            int u = (t >= off) ? sd[t - off] : 0;
            __syncthreads();
            sd[t] += u;
            __syncthreads();
        }
        int excl = sd[t] - v + myBase;
        if (i < N) {
            row_ptr[i] = excl;
            int run = excl;
#pragma unroll
            for (int p = 0; p < NPART; p++) { basep[(size_t)p * N + i] = run; run += c[p]; }
            if (i == N - 1) row_ptr[N] = excl + v;
        }
        __syncthreads();
    }
    grid.sync();

    // phase 4: scatter (no atomics): pos = basep[p][row] + rank8[e]
    for (int b = blockIdx.x; b < nb_edge; b += nblk) {
        int e = b * 256 + t;
        if (e < E) {
            int p = b & (NPART - 1);
            int row = ei[e], col = ei[E + e];
            float d = dist[e];
            int didx = (int)(d * (32768.0f / CUTOFF) + 0.5f);
            didx = max(0, min(didx, 32767));
            int pos = basep[(size_t)p * N + row] + (int)rank8[e];
            __builtin_nontemporal_store(((unsigned)col << 15) | (unsigned)didx, &recs[pos]);
        }
    }
}

// Fused layer: phase A 8 groups x 8 lanes, 2-wide edge unroll (two independent
// rec->gather->fma chains in flight; clamped index, fv zeroed when OOR).
// fs lerped inline from LDS LUT. Phase B: 64x64x2 MLP as 16 MFMAs (fp16, BN
// folded in W2'). fp16 h double-buffered. do_mean: block partial sums of the
// new h into partials[block] (no atomics) — last layer only.
__global__ __launch_bounds__(256)
void k_layer(const int* __restrict__ row_ptr, const unsigned int* __restrict__ recs,
             const float* __restrict__ lutl, const h8* __restrict__ Wsw,
             const float* __restrict__ b1, const float* __restrict__ b2p,
             const _Float16* __restrict__ h_in, _Float16* __restrict__ h_out,
             float* __restrict__ partials, int do_mean, int N) {
    __shared__ float s_lut[LUTN + 1];       // 8196 B
    __shared__ _Float16 sA[64 * ASTRIDE];   // 9216 B
    __shared__ float smean[4][64];          // 1 KB (mean fusion)
    for (int i = threadIdx.x; i <= LUTN; i += 256) s_lut[i] = lutl[i];
    __syncthreads();

    int lane = threadIdx.x & 63;
    int w = threadIdx.x >> 6;
    int base = blockIdx.x * 64 + w * 16;    // this wave's 16 nodes
    int g = lane >> 3, ci = lane & 7;       // 8 groups x 8 lanes
    const uint4* h4 = (const uint4*)h_in;   // 8 halves per uint4; 8 per row

    // ---- phase A: aggregate (packed fp16, 2 edges in flight per group) ----
    for (int i = 0; i < 16; i++) {
        int node = base + i;
        h2 acc[4];
#pragma unroll
        for (int q = 0; q < 4; q++) acc[q] = (h2){(_Float16)0.f, (_Float16)0.f};
        if (node < N) {
            int s = row_ptr[node], t = row_ptr[node + 1];
            for (int k = s + g; k < t; k += 16) {
                int kb = k + 8;
                bool v2 = kb < t;
                int kbc = v2 ? kb : k;          // clamped: always a valid index
                unsigned rec0 = recs[k];
                unsigned rec1 = recs[kbc];
                int c0 = rec0 >> 15;
                int c1 = rec1 >> 15;
                float td0 = (float)(rec0 & 32767u) * (1.0f / 16.0f);
                float td1 = (float)(rec1 & 32767u) * (1.0f / 16.0f);
                int i00 = (int)td0, i01 = (int)td1;
                float fr0 = td0 - (float)i00, fr1 = td1 - (float)i01;
                float f00 = s_lut[i00], f01 = s_lut[i01];
                float fv0 = f00 + fr0 * (s_lut[i00 + 1] - f00);
                float fv1 = f01 + fr1 * (s_lut[i01 + 1] - f01);
                fv1 = v2 ? fv1 : 0.f;
                _Float16 fh0 = (_Float16)fv0, fh1 = (_Float16)fv1;
                h2 fva = (h2){fh0, fh0};
                h2 fvb = (h2){fh1, fh1};
                union { uint4 u; h2 v[4]; } p0, p1;
                p0.u = h4[(size_t)c0 * 8 + ci];
                p1.u = h4[(size_t)c1 * 8 + ci];
#pragma unroll
                for (int q = 0; q < 4; q++) acc[q] += fva * p0.v[q];
#pragma unroll
                for (int q = 0; q < 4; q++) acc[q] += fvb * p1.v[q];
            }
        }
#pragma unroll
        for (int m = 8; m <= 32; m <<= 1) {
#pragma unroll
            for (int q = 0; q < 4; q++) {
                union { h2 v; int u; } a, b;
                a.v = acc[q];
                b.u = __shfl_xor(a.u, m, 64);
                acc[q] += b.v;
            }
        }
        if (g == 0) {
            union { uint4 u4; h2 v[4]; } pk;
#pragma unroll
            for (int q = 0; q < 4; q++) pk.v[q] = acc[q];
            *(uint4*)&sA[(size_t)(w * 16 + i) * ASTRIDE + ci * 8] = pk.u4;
        }
    }
    // wave-private LDS rows: in-wave ds ordering, no barrier needed

    // ---- phase B: MFMA MLP ----
    int q4 = lane >> 4, c16 = lane & 15;
    int rowb = w * 16;
    const h8* WB1 = Wsw;            // frags [kt][nt][lane]
    const h8* WB2 = Wsw + 8 * 64;
    h8 A0 = *(const h8*)&sA[(size_t)(rowb + c16) * ASTRIDE + q4 * 8];
    h8 A1 = *(const h8*)&sA[(size_t)(rowb + c16) * ASTRIDE + 32 + q4 * 8];
    f32x4 C1[4];
#pragma unroll
    for (int nt = 0; nt < 4; nt++) {
        f32x4 c = {0.f, 0.f, 0.f, 0.f};
        c = __builtin_amdgcn_mfma_f32_16x16x32_f16(A0, WB1[nt * 64 + lane], c, 0, 0, 0);
        c = __builtin_amdgcn_mfma_f32_16x16x32_f16(A1, WB1[(4 + nt) * 64 + lane], c, 0, 0, 0);
        C1[nt] = c;
    }
#pragma unroll
    for (int nt = 0; nt < 4; nt++) {
        float bb = b1[nt * 16 + c16];
#pragma unroll
        for (int reg = 0; reg < 4; reg++) {
            float v = softplus_f(C1[nt][reg] + bb);
            sA[(size_t)(rowb + q4 * 4 + reg) * ASTRIDE + nt * 16 + c16] = (_Float16)v;
        }
    }
    h8 M0 = *(const h8*)&sA[(size_t)(rowb + c16) * ASTRIDE + q4 * 8];
    h8 M1 = *(const h8*)&sA[(size_t)(rowb + c16) * ASTRIDE + 32 + q4 * 8];
    f32x4 C2[4];
#pragma unroll
    for (int nt = 0; nt < 4; nt++) {
        f32x4 c = {0.f, 0.f, 0.f, 0.f};
        c = __builtin_amdgcn_mfma_f32_16x16x32_f16(M0, WB2[nt * 64 + lane], c, 0, 0, 0);
        c = __builtin_amdgcn_mfma_f32_16x16x32_f16(M1, WB2[(4 + nt) * 64 + lane], c, 0, 0, 0);
        C2[nt] = c;
    }
    // epilogue: + b2' (BN folded), fp16 residual, dbuf write (+ mean partials)
    float hnv[4][4];
#pragma unroll
    for (int nt = 0; nt < 4; nt++) {
        float bb2 = b2p[nt * 16 + c16];
#pragma unroll
        for (int reg = 0; reg < 4; reg++) {
            int node = base + q4 * 4 + reg;
            bool valid = node < N;
            size_t idx = (size_t)node * H + nt * 16 + c16;
            float hv = valid ? (float)h_in[idx] : 0.f;
            float hn = hv + C2[nt][reg] + bb2;
            if (valid) h_out[idx] = (_Float16)hn;
            hnv[nt][reg] = valid ? hn : 0.f;
        }
    }
    if (do_mean) {
        float s[4];
#pragma unroll
        for (int nt = 0; nt < 4; nt++) {
            s[nt] = hnv[nt][0] + hnv[nt][1] + hnv[nt][2] + hnv[nt][3];
            s[nt] += __shfl_xor(s[nt], 16, 64);
            s[nt] += __shfl_xor(s[nt], 32, 64);
        }
        if (q4 == 0) {
#pragma unroll
            for (int nt = 0; nt < 4; nt++) smean[w][nt * 16 + c16] = s[nt];
        }
        __syncthreads();
        int t2 = threadIdx.x;
        if (t2 < 64) {
            float tot = smean[0][t2] + smean[1][t2] + smean[2][t2] + smean[3][t2];
            partials[(size_t)blockIdx.x * H + t2] = tot;
        }
    }
}

// Final: one block reduces nbp partial rows, then the tiny output MLP.
__global__ __launch_bounds__(256)
void k_final(const float* __restrict__ partials, int nbp, int N,
             const float* __restrict__ oW1, const float* __restrict__ ob1,
             const float* __restrict__ og1, const float* __restrict__ obt1,
             const float* __restrict__ oW2, const float* __restrict__ ob2,
             const float* __restrict__ og2, const float* __restrict__ obt2,
             const float* __restrict__ fin_W, const float* __restrict__ fin_b,
             float* __restrict__ out) {
    __shared__ float red[4][H];
    __shared__ float sg[H], su[H / 2], sv[H / 2];
    int t = threadIdx.x;
    int ch = t & 63, grp = t >> 6;
    float s = 0.f;
    for (int b = grp; b < nbp; b += 4) s += partials[(size_t)b * H + ch];
    red[grp][ch] = s;
    __syncthreads();
    if (t < H) sg[t] = (red[0][t] + red[1][t] + red[2][t] + red[3][t]) / (float)N;
    __syncthreads();
    int j = t;
    if (j < H / 2) {
        float acc = ob1[j];
        for (int k = 0; k < H; k++) acc += sg[k] * oW1[k * (H / 2) + j];
        su[j] = softplus_f(acc) * BN_INV * og1[j] + obt1[j];
    }
    __syncthreads();
    if (j < H / 2) {
        float acc = ob2[j];
        for (int k = 0; k < H / 2; k++) acc += su[k] * oW2[k * (H / 2) + j];
        sv[j] = softplus_f(acc) * BN_INV * og2[j] + obt2[j];
    }
    __syncthreads();
    if (j < 3) {
        float acc = fin_b[j];
        for (int k = 0; k < H / 2; k++) acc += sv[k] * fin_W[k * 3 + j];
        out[j] = acc;
    }
}

extern "C" void kernel_launch(void* const* d_in, const int* in_sizes, int n_in,
                              void* d_out, int out_size, void* d_ws, size_t ws_size,
                              hipStream_t stream) {
    const float* x      = (const float*)d_in[0];
    const int*   ei     = (const int*)d_in[1];
    const float* dist   = (const float*)d_in[2];
    /* d_in[3] edge_attr: unused by reference */
    const float* emb_W  = (const float*)d_in[4];
    const float* emb_b  = (const float*)d_in[5];
    const float* fW1    = (const float*)d_in[6];
    const float* fb1    = (const float*)d_in[7];
    const float* fW2    = (const float*)d_in[8];
    const float* fb2    = (const float*)d_in[9];
    const float* iW1    = (const float*)d_in[10];
    const float* ib1    = (const float*)d_in[11];
    const float* iW2    = (const float*)d_in[12];
    const float* ib2    = (const float*)d_in[13];
    const float* bn_g   = (const float*)d_in[14];
    const float* bn_b   = (const float*)d_in[15];
    const float* oW1    = (const float*)d_in[16];
    const float* ob1    = (const float*)d_in[17];
    const float* og1    = (const float*)d_in[18];
    const float* obt1   = (const float*)d_in[19];
    const float* oW2    = (const float*)d_in[20];
    const float* ob2    = (const float*)d_in[21];
    const float* og2    = (const float*)d_in[22];
    const float* obt2   = (const float*)d_in[23];
    const float* fin_W  = (const float*)d_in[24];
    const float* fin_b  = (const float*)d_in[25];
    float* out = (float*)d_out;

    int N = in_sizes[0] / FIN;
    int E = in_sizes[2];
    int nb_tile = (N + 63) / 64;

    // workspace layout (16B-aligned chunks first)
    float*  ws   = (float*)d_ws;
    _Float16* h0 = (_Float16*)ws;                          // N*H fp16
    _Float16* h1 = h0 + (size_t)N * H;                     // N*H fp16
    unsigned int*  recs = (unsigned int*)(h1 + (size_t)N * H);   // E uint32
    h8*     Wsw  = (h8*)(recs + E);                        // 3*2*8*64 h8
    float*  lut  = (float*)(Wsw + NLAYERS * 2 * 8 * 64);   // 3*LUTSTRIDE
    float*  partials = lut + 3 * LUTSTRIDE;                // nb_tile*H
    float*  b2p  = partials + (size_t)nb_tile * H;         // L*H
    int*    cnt8 = (int*)(b2p + NLAYERS * H);              // NPART*N
    int*    basep = cnt8 + (size_t)NPART * N;              // NPART*N
    int*    row_ptr = basep + (size_t)NPART * N;           // N+1
    int*    bsums   = row_ptr + (N + 1);                   // <=512
    unsigned char* rank8 = (unsigned char*)(bsums + 512);  // E bytes

    int nbE = (N + 3) / 4;
    int nb_setup = nbE + NLAYERS * LUTB + 12;
    k_setup<<<nb_setup, 256, 0, stream>>>(x, emb_W, emb_b, h0,
                                          fW1, fb1, fW2, fb2, iW1, iW2,
                                          bn_g, bn_b, ib2, Wsw, b2p, lut,
                                          cnt8, N);

    {
        const int* a_ei = ei; const float* a_dist = dist;
        int* a_cnt8 = cnt8; unsigned char* a_rank8 = rank8;
        int* a_rp = row_ptr; int* a_bp = basep; int* a_bs = bsums;
        unsigned int* a_recs = recs; int a_N = N; int a_E = E;
        void* args[] = {&a_ei, &a_dist, &a_cnt8, &a_rank8, &a_rp, &a_bp,
                        &a_bs, &a_recs, &a_N, &a_E};
        hipLaunchCooperativeKernel((void*)k_prep, dim3(PREPB), dim3(256),
                                   args, 0, stream);
    }

    _Float16* hp[2] = {h0, h1};
    for (int l = 0; l < NLAYERS; l++) {
        k_layer<<<nb_tile, 256, 0, stream>>>(row_ptr, recs, lut + (size_t)l * LUTSTRIDE,
                                             Wsw + (size_t)l * 1024,
                                             ib1 + l * H, b2p + l * H,
                                             hp[l & 1], hp[(l + 1) & 1],
                                             partials, (l == NLAYERS - 1) ? 1 : 0, N);
    }

    k_final<<<1, 256, 0, stream>>>(partials, nb_tile, N, oW1, ob1, og1, obt1,
                                   oW2, ob2, og2, obt2, fin_W, fin_b, out);
}